// Round 7
// baseline (516.645 us; speedup 1.0000x reference)
//
#include <hip/hip_runtime.h>
#include <cstdint>

typedef unsigned short u16;
typedef short bf16x8 __attribute__((ext_vector_type(8)));
typedef unsigned short u16x8 __attribute__((ext_vector_type(8)));
typedef float f32x4 __attribute__((ext_vector_type(4)));

__device__ __forceinline__ u16 f2bf(float f) {
  union { float f; uint32_t u; } v; v.f = f;
  uint32_t r = (v.u + 0x7fffu + ((v.u >> 16) & 1u)) >> 16;
  return (u16)r;
}

__device__ __forceinline__ void gload_lds16(const u16* g, u16* l) {
  __builtin_amdgcn_global_load_lds(
      (const __attribute__((address_space(1))) void*)g,
      (__attribute__((address_space(3))) void*)l, 16, 0, 0);
}

// ---------------- LayerNorm: fp32 in -> bf16 out, C = 1024 ----------------
__global__ __launch_bounds__(256) void ln_kernel(const float* __restrict__ x,
                                                 u16* __restrict__ h) {
  const int row = blockIdx.x;
  const int tid = threadIdx.x;
  const float4 v = *reinterpret_cast<const float4*>(x + (long)row * 1024 + tid * 4);
  float s  = v.x + v.y + v.z + v.w;
  float ss = v.x * v.x + v.y * v.y + v.z * v.z + v.w * v.w;
#pragma unroll
  for (int off = 32; off >= 1; off >>= 1) {
    s  += __shfl_xor(s, off, 64);
    ss += __shfl_xor(ss, off, 64);
  }
  __shared__ float red[8];
  const int wave = tid >> 6, lane = tid & 63;
  if (lane == 0) { red[wave] = s; red[4 + wave] = ss; }
  __syncthreads();
  s  = red[0] + red[1] + red[2] + red[3];
  ss = red[4] + red[5] + red[6] + red[7];
  const float mu   = s * (1.0f / 1024.0f);
  const float var  = ss * (1.0f / 1024.0f) - mu * mu;
  const float rstd = rsqrtf(var + 1e-6f);
  ushort4 o;
  o.x = f2bf((v.x - mu) * rstd);
  o.y = f2bf((v.y - mu) * rstd);
  o.z = f2bf((v.z - mu) * rstd);
  o.w = f2bf((v.w - mu) * rstd);
  *reinterpret_cast<ushort4*>(h + (long)row * 1024 + tid * 4) = o;
}

// ------------- merged weight transpose+convert: W[K][N] fp32 -> Wt[N][K] bf16 ----------
struct WEnt { const float* W; u16* Wt; int K, N, tEnd; };
struct WEnts { WEnt e[7]; int n; };

__global__ __launch_bounds__(256) void wconvert_all(WEnts args) {
  __shared__ u16 tile[64][72];
  int t = blockIdx.x;
  int i = 0, tStart = 0;
  while (i < args.n - 1 && t >= args.e[i].tEnd) { tStart = args.e[i].tEnd; i++; }
  const float* W = args.e[i].W;
  u16* Wt = args.e[i].Wt;
  const int K = args.e[i].K, N = args.e[i].N;
  const int rel = t - tStart;
  const int ntn = N >> 6;
  const int tn = rel % ntn, tk = rel / ntn;
  const int n0 = tn * 64, k0 = tk * 64;

  const int th = threadIdx.x;
  const int c4 = (th & 15) * 4;
  const int r  = th >> 4;
#pragma unroll
  for (int ii = 0; ii < 4; ii++) {
    const int row = ii * 16 + r;
    const float4 v = *reinterpret_cast<const float4*>(W + (long)(k0 + row) * N + n0 + c4);
    tile[c4 + 0][row] = f2bf(v.x);
    tile[c4 + 1][row] = f2bf(v.y);
    tile[c4 + 2][row] = f2bf(v.z);
    tile[c4 + 3][row] = f2bf(v.w);
  }
  __syncthreads();
  const int c8 = (th & 7) * 8;
  const int rn = th >> 3;
#pragma unroll
  for (int ii = 0; ii < 2; ii++) {
    const int row = ii * 32 + rn;
    *reinterpret_cast<u16x8*>(Wt + (long)(n0 + row) * K + k0 + c8) =
        *reinterpret_cast<const u16x8*>(&tile[row][c8]);
  }
}

// ---------------- fp32 -> bf16 elementwise ----------------
__global__ __launch_bounds__(256) void f2bf_kernel(const float* __restrict__ in,
                                                   u16* __restrict__ out) {
  const long i = ((long)blockIdx.x * 256 + threadIdx.x) * 4;
  const float4 v = *reinterpret_cast<const float4*>(in + i);
  ushort4 o;
  o.x = f2bf(v.x); o.y = f2bf(v.y); o.z = f2bf(v.z); o.w = f2bf(v.w);
  *reinterpret_cast<ushort4*>(out + i) = o;
}

// ------- V transpose (coalesced LDS-tile): V[b][n][..h*64+d] -> Vt[(b*16+h)][d][nk] ----
__global__ __launch_bounds__(256) void vtrans(const u16* __restrict__ V,
                                              u16* __restrict__ Vt,
                                              int vStride, long vBatch, int nk) {
  __shared__ u16 tile[64][72];
  const int t = threadIdx.x;
  const int b = blockIdx.z, h = blockIdx.y, n0 = blockIdx.x * 64;
  const u16* vp = V + (long)b * vBatch + h * 64;
  u16* op = Vt + (long)(b * 16 + h) * 64 * (long)nk + n0;
  const int ch = t & 7;
#pragma unroll
  for (int i = 0; i < 2; i++) {
    const int n = (t >> 3) + i * 32;
    const u16x8 v = *reinterpret_cast<const u16x8*>(vp + (long)(n0 + n) * vStride + ch * 8);
#pragma unroll
    for (int j = 0; j < 8; j++) tile[ch * 8 + j][n] = v[j];
  }
  __syncthreads();
#pragma unroll
  for (int i = 0; i < 2; i++) {
    const int d = (t >> 3) + i * 32;
    *reinterpret_cast<u16x8*>(op + (long)d * nk + ch * 8) =
        *reinterpret_cast<const u16x8*>(&tile[d][ch * 8]);
  }
}

// --- GEMM v3 (dbuf prefetch + XCD swizzle + optional split-K atomic accumulate) --------
// blockIdx.y = k-chunk (ATOMIC only): handles K range [kc*KC, (kc+1)*KC), atomicAdds
// partial into fp32 Cout (which must already hold the residual); kc==0 adds bias.
template <int TN, int SX, bool OUT_BF16, bool GELU_ACT, bool RES, bool ATOMIC>
__global__ __launch_bounds__(256, 2) void gemm_bt(
    const u16* __restrict__ A, const u16* __restrict__ Bt,
    const float* __restrict__ bias, const float* __restrict__ res,
    void* __restrict__ Cout, int Ndim, int lx, int ly, int KC, int Kdim) {
  constexpr int NFRAG = TN / 32;
  __shared__ u16 Al[2][128 * 32];
  __shared__ u16 Bl[2][TN * 32];
  const int j = blockIdx.x;
  const int c = j & 7, kk = j >> 3;
  const int cx = c % SX, cy = c / SX;
  const int bx = cx * lx + (kk % lx);
  const int by = cy * ly + (kk / lx);
  const int m0 = by * 128, n0 = bx * TN;
  const int kc = ATOMIC ? blockIdx.y : 0;
  const int kOff = kc * KC;

  const int tid  = threadIdx.x;
  const int lane = tid & 63, wave = tid >> 6;
  const int quad = lane >> 4, l15 = lane & 15;
  const int wr = wave >> 1, wc = wave & 1;

  f32x4 acc[4][NFRAG];
  const f32x4 vzero = {0.f, 0.f, 0.f, 0.f};
#pragma unroll
  for (int i = 0; i < 4; i++)
#pragma unroll
    for (int jj = 0; jj < NFRAG; jj++) acc[i][jj] = vzero;

  const long rowOff = (long)(lane >> 2) * Kdim + (lane & 3) * 8;
  const u16* gA = A  + (long)m0 * Kdim + rowOff;
  const u16* gB = Bt + (long)n0 * Kdim + rowOff;

  auto stage = [&](int k0, int p) {
    gload_lds16(gA + (long)(wave * 16) * Kdim + k0,       &Al[p][wave * 512]);
    gload_lds16(gA + (long)((wave + 4) * 16) * Kdim + k0, &Al[p][(wave + 4) * 512]);
    gload_lds16(gB + (long)(wave * 16) * Kdim + k0,       &Bl[p][wave * 512]);
    if constexpr (TN == 128)
      gload_lds16(gB + (long)((wave + 4) * 16) * Kdim + k0, &Bl[p][(wave + 4) * 512]);
  };

  stage(kOff, 0);
  int p = 0;
  const int kEnd = kOff + KC;
  for (int k0 = kOff; k0 < kEnd; k0 += 32, p ^= 1) {
    __syncthreads();
    bf16x8 af[4], bfr[NFRAG];
#pragma unroll
    for (int mt = 0; mt < 4; mt++)
      af[mt] = *reinterpret_cast<const bf16x8*>(&Al[p][(wr * 64 + mt * 16 + l15) * 32 + quad * 8]);
#pragma unroll
    for (int nt = 0; nt < NFRAG; nt++)
      bfr[nt] = *reinterpret_cast<const bf16x8*>(&Bl[p][(wc * NFRAG * 16 + nt * 16 + l15) * 32 + quad * 8]);
    if (k0 + 32 < kEnd) stage(k0 + 32, p ^ 1);
#pragma unroll
    for (int mt = 0; mt < 4; mt++)
#pragma unroll
      for (int nt = 0; nt < NFRAG; nt++)
        acc[mt][nt] = __builtin_amdgcn_mfma_f32_16x16x32_bf16(af[mt], bfr[nt], acc[mt][nt], 0, 0, 0);
  }

#pragma unroll
  for (int nt = 0; nt < NFRAG; nt++) {
    const int col = n0 + wc * NFRAG * 16 + nt * 16 + l15;
    const float bv = bias[col];
#pragma unroll
    for (int mt = 0; mt < 4; mt++) {
#pragma unroll
      for (int r = 0; r < 4; r++) {
        const int row = m0 + wr * 64 + mt * 16 + quad * 4 + r;
        float y = acc[mt][nt][r];
        if (ATOMIC) {
          if (kc == 0) y += bv;
          atomicAdd((float*)Cout + (long)row * Ndim + col, y);
        } else {
          y += bv;
          if (GELU_ACT) {
            const float t = 0.7978845608028654f * (y + 0.044715f * y * y * y);
            y = 0.5f * y * (1.0f + tanhf(t));
          }
          if (RES) y += res[(long)row * Ndim + col];
          if (OUT_BF16)
            ((u16*)Cout)[(long)row * Ndim + col] = f2bf(y);
          else
            ((float*)Cout)[(long)row * Ndim + col] = y;
        }
      }
    }
  }
}

// ------- Flash attention v4: dbuf prefetch, 128 q/block, XOR-8 swizzle, no-max ---------
__global__ __launch_bounds__(256, 2) void attn_kernel(
    const u16* __restrict__ Q, const u16* __restrict__ K, const u16* __restrict__ Vt,
    u16* __restrict__ O, int nk, int qStride, int kStride, int oStride,
    long qBatch, long kBatch, long oBatch) {
  __shared__ u16 Kt[2][64 * 64];
  __shared__ u16 Vl[2][64 * 64];
  __shared__ u16 Pl[4][32 * 64];

  const int tid = threadIdx.x;
  const int lane = tid & 63, wave = tid >> 6;
  const int quad = lane >> 4, l15 = lane & 15;
  const int b = blockIdx.z, hh = blockIdx.y, qt = blockIdx.x;

  const u16* qp = Q + (long)b * qBatch + hh * 64;
  const u16* kp = K + (long)b * kBatch + hh * 64;
  const u16* vp = Vt + (long)(b * 16 + hh) * 64 * (long)nk;

  bf16x8 qf[2][2];
  const int qrow = qt * 128 + wave * 32 + l15;
#pragma unroll
  for (int qg = 0; qg < 2; qg++) {
    qf[qg][0] = *reinterpret_cast<const bf16x8*>(qp + (long)(qrow + qg * 16) * qStride + quad * 8);
    qf[qg][1] = *reinterpret_cast<const bf16x8*>(qp + (long)(qrow + qg * 16) * qStride + 32 + quad * 8);
  }

  const int r8 = lane >> 3;
  const int gcol = ((lane & 7) ^ r8) * 8;
  const u16* kgA = kp + (long)(wave * 8 + r8) * kStride + gcol;
  const u16* kgB = kp + (long)((wave + 4) * 8 + r8) * kStride + gcol;
  const u16* vgA = vp + (long)(wave * 8 + r8) * nk + gcol;
  const u16* vgB = vp + (long)((wave + 4) * 8 + r8) * nk + gcol;

  const int cF = (quad ^ (l15 & 7)) * 8;

  const f32x4 vzero = {0.f, 0.f, 0.f, 0.f};
  f32x4 oAcc[2][4];
  float lSt[2] = {0.f, 0.f};
#pragma unroll
  for (int qg = 0; qg < 2; qg++)
#pragma unroll
    for (int i = 0; i < 4; i++) oAcc[qg][i] = vzero;

  const float SCL = 0.18033688f;
  const int nTiles = nk >> 6;
  const long kAdv = (long)64 * kStride;

  auto stage = [&](int kt, int p) {
    gload_lds16(kgA + kt * kAdv, &Kt[p][wave * 512]);
    gload_lds16(kgB + kt * kAdv, &Kt[p][(wave + 4) * 512]);
    gload_lds16(vgA + kt * 64,   &Vl[p][wave * 512]);
    gload_lds16(vgB + kt * 64,   &Vl[p][(wave + 4) * 512]);
  };

  stage(0, 0);
  int p = 0;
  for (int kt = 0; kt < nTiles; kt++, p ^= 1) {
    __syncthreads();
    if (kt + 1 < nTiles) stage(kt + 1, p ^ 1);

    f32x4 st[2][4];
#pragma unroll
    for (int mt = 0; mt < 4; mt++) {
      const bf16x8 kf0 = *reinterpret_cast<const bf16x8*>(&Kt[p][(mt * 16 + l15) * 64 + cF]);
      const bf16x8 kf1 = *reinterpret_cast<const bf16x8*>(&Kt[p][(mt * 16 + l15) * 64 + (cF ^ 32)]);
#pragma unroll
      for (int qg = 0; qg < 2; qg++) {
        f32x4 z = vzero;
        z = __builtin_amdgcn_mfma_f32_16x16x32_bf16(kf0, qf[qg][0], z, 0, 0, 0);
        z = __builtin_amdgcn_mfma_f32_16x16x32_bf16(kf1, qf[qg][1], z, 0, 0, 0);
        st[qg][mt] = z;
      }
    }

#pragma unroll
    for (int qg = 0; qg < 2; qg++) {
      float ps = 0.f;
#pragma unroll
      for (int mt = 0; mt < 4; mt++)
#pragma unroll
        for (int r = 0; r < 4; r++) {
          const float pw = __builtin_amdgcn_exp2f(st[qg][mt][r] * SCL);
          st[qg][mt][r] = pw;
          ps += pw;
        }
      lSt[qg] += ps;
      u16* plw = &Pl[wave][(qg * 16 + l15) * 64];
#pragma unroll
      for (int mt = 0; mt < 4; mt++) {
        union { float f; uint32_t u; } a0, a1, a2, a3;
        a0.f = st[qg][mt][0]; a1.f = st[qg][mt][1];
        a2.f = st[qg][mt][2]; a3.f = st[qg][mt][3];
        a0.u += 0x8000u; a1.u += 0x8000u; a2.u += 0x8000u; a3.u += 0x8000u;
        uint2 w;
        w.x = __builtin_amdgcn_perm(a1.u, a0.u, 0x07060302u);
        w.y = __builtin_amdgcn_perm(a3.u, a2.u, 0x07060302u);
        const int pcol = (((mt * 2 + (quad >> 1)) ^ (l15 & 7)) * 8) + (quad & 1) * 4;
        *reinterpret_cast<uint2*>(&plw[pcol]) = w;
      }
    }

    bf16x8 pf[2][2];
#pragma unroll
    for (int qg = 0; qg < 2; qg++) {
      const u16* plw = &Pl[wave][(qg * 16 + l15) * 64];
      pf[qg][0] = *reinterpret_cast<const bf16x8*>(&plw[cF]);
      pf[qg][1] = *reinterpret_cast<const bf16x8*>(&plw[cF ^ 32]);
    }
#pragma unroll
    for (int dt = 0; dt < 4; dt++) {
      const bf16x8 vf0 = *reinterpret_cast<const bf16x8*>(&Vl[p][(dt * 16 + l15) * 64 + cF]);
      const bf16x8 vf1 = *reinterpret_cast<const bf16x8*>(&Vl[p][(dt * 16 + l15) * 64 + (cF ^ 32)]);
#pragma unroll
      for (int qg = 0; qg < 2; qg++) {
        oAcc[qg][dt] = __builtin_amdgcn_mfma_f32_16x16x32_bf16(pf[qg][0], vf0, oAcc[qg][dt], 0, 0, 0);
        oAcc[qg][dt] = __builtin_amdgcn_mfma_f32_16x16x32_bf16(pf[qg][1], vf1, oAcc[qg][dt], 0, 0, 0);
      }
    }
  }

  u16* op = O + (long)b * oBatch + hh * 64;
#pragma unroll
  for (int qg = 0; qg < 2; qg++) {
    float l = lSt[qg];
    l += __shfl_xor(l, 16, 64);
    l += __shfl_xor(l, 32, 64);
    float lR[4];
#pragma unroll
    for (int r = 0; r < 4; r++) lR[r] = 1.0f / __shfl(l, quad * 4 + r, 64);
#pragma unroll
    for (int dt = 0; dt < 4; dt++)
#pragma unroll
      for (int r = 0; r < 4; r++) {
        const int row = qt * 128 + wave * 32 + qg * 16 + quad * 4 + r;
        op[(long)row * oStride + dt * 16 + l15] = f2bf(oAcc[qg][dt][r] * lR[r]);
      }
  }
}

// ---------------- launcher ----------------
extern "C" void kernel_launch(void* const* d_in, const int* in_sizes, int n_in,
                              void* d_out, int out_size, void* d_ws, size_t ws_size,
                              hipStream_t stream) {
  const float* x    = (const float*)d_in[0];
  const float* ctx  = (const float*)d_in[1];
  const float* Wqkv = (const float*)d_in[2];
  const float* bqkv = (const float*)d_in[3];
  const float* Wos  = (const float*)d_in[4];
  const float* bos  = (const float*)d_in[5];
  const float* Wq   = (const float*)d_in[6];
  const float* bq   = (const float*)d_in[7];
  const float* Wkv  = (const float*)d_in[8];
  const float* bkv  = (const float*)d_in[9];
  const float* Woc  = (const float*)d_in[10];
  const float* boc  = (const float*)d_in[11];
  const float* W1   = (const float*)d_in[12];
  const float* b1   = (const float*)d_in[13];
  const float* W2   = (const float*)d_in[14];
  const float* b2   = (const float*)d_in[15];
  float* out = (float*)d_out;
  char* ws = (char*)d_ws;
  const size_t MB = 1024 * 1024;

  if (ws_size >= 80 * MB) {
    u16* Wqkvt = (u16*)(ws + 0 * MB);
    u16* Wost  = (u16*)(ws + 6 * MB);
    u16* Wqt   = (u16*)(ws + 8 * MB);
    u16* Wkvt  = (u16*)(ws + 10 * MB);
    u16* Woct  = (u16*)(ws + 14 * MB);
    u16* W1t   = (u16*)(ws + 16 * MB);
    u16* W2t   = (u16*)(ws + 24 * MB);
    u16* h     = (u16*)(ws + 32 * MB);
    u16* abuf  = (u16*)(ws + 40 * MB);
    u16* qkv   = (u16*)(ws + 48 * MB);
    u16* q2    = (u16*)(ws + 48 * MB);
    u16* kv2   = (u16*)(ws + 56 * MB);
    u16* ctxbf = (u16*)(ws + 64 * MB);
    u16* VtCr  = (u16*)(ws + 68 * MB);
    u16* hid   = (u16*)(ws + 48 * MB);
    u16* VtSelf = h;

    WEnts we;
    we.n = 7;
    we.e[0] = {Wqkv, Wqkvt, 1024, 3072, 768};
    we.e[1] = {Wos,  Wost,  1024, 1024, 1024};
    we.e[2] = {Wq,   Wqt,   1024, 1024, 1280};
    we.e[3] = {Wkv,  Wkvt,  1024, 2048, 1792};
    we.e[4] = {Woc,  Woct,  1024, 1024, 2048};
    we.e[5] = {W1,   W1t,   1024, 4096, 3072};
    we.e[6] = {W2,   W2t,   4096, 1024, 4096};
    wconvert_all<<<dim3(4096), dim3(256), 0, stream>>>(we);
    f2bf_kernel<<<dim3(2048), dim3(256), 0, stream>>>(ctx, ctxbf);

    ln_kernel<<<dim3(4096), dim3(256), 0, stream>>>(x, h);
    gemm_bt<128, 2, true, false, false, false><<<dim3(768), dim3(256), 0, stream>>>(
        h, Wqkvt, bqkv, nullptr, qkv, 3072, 12, 8, 1024, 1024);
    vtrans<<<dim3(32, 16, 2), dim3(256), 0, stream>>>(
        qkv + 2048, VtSelf, 3072, (long)2048 * 3072, 2048);
    attn_kernel<<<dim3(16, 16, 2), dim3(256), 0, stream>>>(
        qkv, qkv + 1024, VtSelf, abuf, 2048, 3072, 3072, 1024,
        (long)2048 * 3072, (long)2048 * 3072, (long)2048 * 1024);
    gemm_bt<64, 1, false, false, true, false><<<dim3(512), dim3(256), 0, stream>>>(
        abuf, Wost, bos, x, out, 1024, 16, 4, 1024, 1024);
    ln_kernel<<<dim3(4096), dim3(256), 0, stream>>>(out, h);
    gemm_bt<64, 1, true, false, false, false><<<dim3(512), dim3(256), 0, stream>>>(
        h, Wqt, bq, nullptr, q2, 1024, 16, 4, 1024, 1024);
    gemm_bt<64, 2, true, false, false, false><<<dim3(512), dim3(256), 0, stream>>>(
        ctxbf, Wkvt, bkv, nullptr, kv2, 2048, 16, 4, 1024, 1024);
    vtrans<<<dim3(16, 16, 2), dim3(256), 0, stream>>>(
        kv2 + 1024, VtCr, 2048, (long)1024 * 2048, 1024);
    attn_kernel<<<dim3(16, 16, 2), dim3(256), 0, stream>>>(
        q2, kv2, VtCr, abuf, 1024, 1024, 2048, 1024,
        (long)2048 * 1024, (long)1024 * 2048, (long)2048 * 1024);
    // out += abuf @ Woc + boc  (split-K 2, atomic accumulate; out already holds residual)
    gemm_bt<64, 1, false, false, false, true><<<dim3(512, 2), dim3(256), 0, stream>>>(
        abuf, Woct, boc, nullptr, out, 1024, 16, 4, 512, 1024);
    ln_kernel<<<dim3(4096), dim3(256), 0, stream>>>(out, h);
    gemm_bt<128, 2, true, true, false, false><<<dim3(1024), dim3(256), 0, stream>>>(
        h, W1t, b1, nullptr, hid, 4096, 16, 8, 1024, 1024);
    // out += hid @ W2 + b2  (split-K 4, atomic accumulate)
    gemm_bt<128, 2, false, false, false, true><<<dim3(256, 4), dim3(256), 0, stream>>>(
        hid, W2t, b2, nullptr, out, 1024, 4, 8, 1024, 4096);
  } else {
    u16* h      = (u16*)ws;
    u16* wbuf   = (u16*)(ws + 8 * MB);
    char* C0    = ws + 16 * MB;
    u16* qkv    = (u16*)C0;
    u16* Wqkvt  = (u16*)(C0 + 24 * MB);
    u16* Wost   = (u16*)C0;
    u16* q2     = (u16*)C0;
    u16* kv2    = (u16*)(C0 + 8 * MB);
    u16* Wqt    = (u16*)(C0 + 16 * MB);
    u16* Wkvt   = (u16*)(C0 + 16 * MB);
    u16* ctxbf  = (u16*)(C0 + 20 * MB);
    u16* VtCr   = (u16*)(C0 + 24 * MB);
    u16* Woct   = (u16*)(C0 + 16 * MB);
    u16* hid    = (u16*)C0;
    u16* VtSelf = h;
    u16* abuf   = wbuf;
    u16* W1t    = wbuf;
    u16* W2t    = wbuf;
    WEnts w1; w1.n = 1;

    ln_kernel<<<dim3(4096), dim3(256), 0, stream>>>(x, h);
    w1.e[0] = {Wqkv, Wqkvt, 1024, 3072, 768};
    wconvert_all<<<dim3(768), dim3(256), 0, stream>>>(w1);
    gemm_bt<128, 2, true, false, false, false><<<dim3(768), dim3(256), 0, stream>>>(
        h, Wqkvt, bqkv, nullptr, qkv, 3072, 12, 8, 1024, 1024);
    vtrans<<<dim3(32, 16, 2), dim3(256), 0, stream>>>(
        qkv + 2048, VtSelf, 3072, (long)2048 * 3072, 2048);
    attn_kernel<<<dim3(16, 16, 2), dim3(256), 0, stream>>>(
        qkv, qkv + 1024, VtSelf, abuf, 2048, 3072, 3072, 1024,
        (long)2048 * 3072, (long)2048 * 3072, (long)2048 * 1024);
    w1.e[0] = {Wos, Wost, 1024, 1024, 256};
    wconvert_all<<<dim3(256), dim3(256), 0, stream>>>(w1);
    gemm_bt<64, 1, false, false, true, false><<<dim3(512), dim3(256), 0, stream>>>(
        abuf, Wost, bos, x, out, 1024, 16, 4, 1024, 1024);
    ln_kernel<<<dim3(4096), dim3(256), 0, stream>>>(out, h);
    w1.e[0] = {Wq, Wqt, 1024, 1024, 256};
    wconvert_all<<<dim3(256), dim3(256), 0, stream>>>(w1);
    gemm_bt<64, 1, true, false, false, false><<<dim3(512), dim3(256), 0, stream>>>(
        h, Wqt, bq, nullptr, q2, 1024, 16, 4, 1024, 1024);
    f2bf_kernel<<<dim3(2048), dim3(256), 0, stream>>>(ctx, ctxbf);
    w1.e[0] = {Wkv, Wkvt, 1024, 2048, 512};
    wconvert_all<<<dim3(512), dim3(256), 0, stream>>>(w1);
    gemm_bt<64, 2, true, false, false, false><<<dim3(512), dim3(256), 0, stream>>>(
        ctxbf, Wkvt, bkv, nullptr, kv2, 2048, 16, 4, 1024, 1024);
    vtrans<<<dim3(16, 16, 2), dim3(256), 0, stream>>>(
        kv2 + 1024, VtCr, 2048, (long)1024 * 2048, 1024);
    attn_kernel<<<dim3(16, 16, 2), dim3(256), 0, stream>>>(
        q2, kv2, VtCr, abuf, 1024, 1024, 2048, 1024,
        (long)2048 * 1024, (long)1024 * 2048, (long)2048 * 1024);
    w1.e[0] = {Woc, Woct, 1024, 1024, 256};
    wconvert_all<<<dim3(256), dim3(256), 0, stream>>>(w1);
    gemm_bt<64, 1, false, false, false, true><<<dim3(512, 2), dim3(256), 0, stream>>>(
        abuf, Woct, boc, nullptr, out, 1024, 16, 4, 512, 1024);
    ln_kernel<<<dim3(4096), dim3(256), 0, stream>>>(out, h);
    w1.e[0] = {W1, W1t, 1024, 4096, 1024};
    wconvert_all<<<dim3(1024), dim3(256), 0, stream>>>(w1);
    gemm_bt<128, 2, true, true, false, false><<<dim3(1024), dim3(256), 0, stream>>>(
        h, W1t, b1, nullptr, hid, 4096, 16, 8, 1024, 1024);
    w1.e[0] = {W2, W2t, 4096, 1024, 1024};
    wconvert_all<<<dim3(1024), dim3(256), 0, stream>>>(w1);
    gemm_bt<128, 2, false, false, false, true><<<dim3(256, 4), dim3(256), 0, stream>>>(
        hid, W2t, b2, nullptr, out, 1024, 4, 8, 1024, 4096);
  }
}